// Round 10
// baseline (378.178 us; speedup 1.0000x reference)
//
#include <hip/hip_runtime.h>
#include <hip/hip_bf16.h>
#include <cstdint>
#include <cstddef>

#define B_ 2
#define S_ 2048
#define D_ 2048
#define H_ 16
#define HD_ 128

typedef __bf16 bf16_t;
typedef __bf16 bf16x8 __attribute__((ext_vector_type(8)));
typedef __bf16 bf16x4 __attribute__((ext_vector_type(4)));
typedef short s16x4 __attribute__((ext_vector_type(4)));
typedef float f32x4 __attribute__((ext_vector_type(4)));

__device__ __forceinline__ void async16(const bf16_t* g, bf16_t* l) {
    __builtin_amdgcn_global_load_lds(
        (const __attribute__((address_space(1))) unsigned int*)g,
        (__attribute__((address_space(3))) unsigned int*)l, 16, 0, 0);
}

// K=16 bf16 MFMA with builtin-name portability chain
__device__ __forceinline__ f32x4 mfma16x16x16_bf16(bf16x4 a, bf16x4 b, f32x4 c) {
#if __has_builtin(__builtin_amdgcn_mfma_f32_16x16x16_bf16)
    return __builtin_amdgcn_mfma_f32_16x16x16_bf16(a, b, c, 0, 0, 0);
#elif __has_builtin(__builtin_amdgcn_mfma_f32_16x16x16bf16_1k)
    return __builtin_amdgcn_mfma_f32_16x16x16bf16_1k(
        __builtin_bit_cast(s16x4, a), __builtin_bit_cast(s16x4, b), c, 0, 0, 0);
#else
    f32x4 d = c;
    asm("v_mfma_f32_16x16x16_bf16 %0, %1, %2, %0" : "+v"(d) : "v"(a), "v"(b));
    return d;
#endif
}

// ---------------- fused fp32 -> bf16 convert; Wq gets 1/sqrt(HD) folded in ----------------
__global__ void f2b_multi(const float* __restrict__ x, const float* __restrict__ wq,
                          const float* __restrict__ wk, const float* __restrict__ wv,
                          const float* __restrict__ wo, bf16_t* __restrict__ xb,
                          bf16_t* __restrict__ wqb, bf16_t* __restrict__ wkb,
                          bf16_t* __restrict__ wvb, bf16_t* __restrict__ wob) {
    const float* in; bf16_t* out;
    float sc = 1.0f;
    switch (blockIdx.y) {
        case 0: in = x;            out = xb;            break;
        case 1: in = x + 4194304;  out = xb + 4194304;  break;
        case 2: in = wq;           out = wqb; sc = 0.08838834764831845f; break;
        case 3: in = wk;           out = wkb;           break;
        case 4: in = wv;           out = wvb;           break;
        default: in = wo;          out = wob;           break;
    }
    int i = (blockIdx.x * blockDim.x + threadIdx.x) * 4;
    float4 v = *(const float4*)(in + i);
    bf16x4 o = { (bf16_t)(v.x * sc), (bf16_t)(v.y * sc), (bf16_t)(v.z * sc), (bf16_t)(v.w * sc) };
    *(bf16x4*)(out + i) = o;
}

// =====================================================================================
// gemm_qkv v4 (r10): 256x128 tile, 512 thr / 8 waves, single 48 KB buffer, simple
// 2-barrier K-loop (the proven multi-block structure — pipelining closed after 3
// strikes r2/r3/r5; T1 swizzle closed after r9's 3x FETCH thrash). vs 128²:
// staging B/elem 64->48, barrier drains per MFMA halved, same 1024 thr/CU occupancy
// (2 blocks x 512 vs 4 x 256). Swizzle unchanged: phys chunk = logical ^ (row&7),
// pre-swizzled global src + linear LDS dest; read pc=(kk*4+hi)^(lo&7) -> 0 conflicts.
// Wave grid: wm=w>>1 (4 m-bands of 64), wn=w&1 (2 n-halves of 64); per-wave 64x64.
// RoPE epilogue: wn=0 waves hold d<64, wn=1 hold d>=64 at identical lane coords
// (pairs w=2wm <-> 2wm+1); 4-slot (wm) 64 KB f32 exchange, same XOR layout as r6.
// __launch_bounds__(512,4) pins VGPR<=128 so 2 blocks/CU hold.
// =====================================================================================
// grid (48, 16): seg = bx>>4 (0=q,1=k,2=v), n0 = (bx&15)*128, m0 = by*256.
__global__ __launch_bounds__(512, 4) void gemm_qkv(const bf16_t* __restrict__ A,
                                                   const bf16_t* __restrict__ Wq,
                                                   const bf16_t* __restrict__ Wk,
                                                   const bf16_t* __restrict__ Wv,
                                                   bf16_t* __restrict__ qb,
                                                   bf16_t* __restrict__ kb,
                                                   bf16_t* __restrict__ vtb) {
    __shared__ __align__(16) bf16_t smem[32768];  // 64 KB: GEMM uses 48 KB; rope exchange uses all 64
    bf16_t* As = smem;            // 256 x 64 = 16384 elems
    bf16_t* Bs = smem + 16384;    // 128 x 64 =  8192 elems
    const int K = D_;
    int t = threadIdx.x;
    int w = t >> 6, lane = t & 63, lo = lane & 15, hi = lane >> 4;
    int seg = blockIdx.x >> 4;
    int n0 = (blockIdx.x & 15) * 128;
    int m0 = blockIdx.y * 256;
    const bf16_t* Bt = (seg == 0) ? Wq : (seg == 1) ? Wk : Wv;
    int wm = w >> 1, wn = w & 1;          // per-wave output 64x64 at (wm*64, wn*64)
    f32x4 acc[4][4] = {};
    // staging: 512 threads cover 64 rows x 64 cols per sweep (8 KB); A 4 sweeps, B 2
    int srow = t >> 3;                                  // 0..63
    int scol = ((t & 7) ^ ((t >> 3) & 7)) * 8;          // pre-swizzled global col
    const bf16_t* gA = A  + (size_t)(m0 + srow) * K + scol;
    const bf16_t* gB = Bt + (size_t)(n0 + srow) * K + scol;
    bf16_t* dA = As + t * 8;
    bf16_t* dB = Bs + t * 8;

    for (int k0 = 0; k0 < K; k0 += 64) {
#pragma unroll
        for (int s = 0; s < 4; ++s)
            async16(gA + (size_t)(s * 64) * K + k0, dA + s * 4096);
#pragma unroll
        for (int s = 0; s < 2; ++s)
            async16(gB + (size_t)(s * 64) * K + k0, dB + s * 4096);
        __syncthreads();
#pragma unroll
        for (int kk = 0; kk < 2; ++kk) {
            bf16x8 af[4], bfr[4];
            int pc = (kk * 4 + hi) ^ (lo & 7);
#pragma unroll
            for (int ms = 0; ms < 4; ++ms)
                af[ms] = *(const bf16x8*)(As + (wm * 64 + ms * 16 + lo) * 64 + pc * 8);
#pragma unroll
            for (int ns = 0; ns < 4; ++ns)
                bfr[ns] = *(const bf16x8*)(Bs + (wn * 64 + ns * 16 + lo) * 64 + pc * 8);
#pragma unroll
            for (int ms = 0; ms < 4; ++ms)
#pragma unroll
                for (int ns = 0; ns < 4; ++ns)
                    acc[ms][ns] = __builtin_amdgcn_mfma_f32_16x16x32_bf16(af[ms], bfr[ns], acc[ms][ns], 0, 0, 0);
        }
        __syncthreads();
    }

    if (seg == 2) {
        // V transposed: vtb[b][d][s] (no rope on V)
#pragma unroll
        for (int ms = 0; ms < 4; ++ms) {
            int mrow = m0 + wm * 64 + ms * 16 + hi * 4;
            int bb = mrow >> 11, s = mrow & (S_ - 1);
#pragma unroll
            for (int ns = 0; ns < 4; ++ns) {
                int d = n0 + wn * 64 + ns * 16 + lo;
                bf16x4 pv = { (bf16_t)acc[ms][ns][0], (bf16_t)acc[ms][ns][1],
                              (bf16_t)acc[ms][ns][2], (bf16_t)acc[ms][ns][3] };
                *(bf16x4*)(vtb + (size_t)bb * D_ * S_ + (size_t)d * S_ + s) = pv;
            }
        }
        return;
    }

    // ---------------- RoPE-fused q/k epilogue (4 wave-pairs) ----------------
    bf16_t* C = (seg == 0) ? qb : kb;
    f32x4* xt = (f32x4*)smem;           // 4096 f32x4 = 64 KB, four 64x64 tiles
    int slot = wm;
    bool upper = (wn != 0);             // holds d in [64,128)

    if (upper) {
#pragma unroll
        for (int ms = 0; ms < 4; ++ms)
#pragma unroll
            for (int ns = 0; ns < 4; ++ns) {
                int c = ns * 16 + lo, j = ms * 4 + hi;
                xt[slot * 1024 + c * 16 + (j ^ (c & 15))] = acc[ms][ns];
            }
    }
    __syncthreads();
    if (!upper) {
        // d = c in [0,64): out = x*cos - x[d+64]*sin
#pragma unroll
        for (int ns = 0; ns < 4; ++ns) {
            int c = ns * 16 + lo;
            float inv = __expf(-(float)c * 0.14391156831212787f);
#pragma unroll
            for (int ms = 0; ms < 4; ++ms) {
                int j = ms * 4 + hi;
                f32x4 pv = xt[slot * 1024 + c * 16 + (j ^ (c & 15))];
#pragma unroll
                for (int r = 0; r < 4; ++r) {
                    int row = m0 + wm * 64 + ms * 16 + hi * 4 + r;
                    float ang = (float)(row & (S_ - 1)) * inv;
                    float sn, cs;
                    __sincosf(ang, &sn, &cs);
                    C[(size_t)row * D_ + n0 + c] = (bf16_t)(acc[ms][ns][r] * cs - pv[r] * sn);
                }
            }
        }
    }
    __syncthreads();
    if (!upper) {
#pragma unroll
        for (int ms = 0; ms < 4; ++ms)
#pragma unroll
            for (int ns = 0; ns < 4; ++ns) {
                int c = ns * 16 + lo, j = ms * 4 + hi;
                xt[slot * 1024 + c * 16 + (j ^ (c & 15))] = acc[ms][ns];
            }
    }
    __syncthreads();
    if (upper) {
        // d = 64 + c: out = x*cos + x[d-64]*sin  (cos/sin index = c)
#pragma unroll
        for (int ns = 0; ns < 4; ++ns) {
            int c = ns * 16 + lo;
            float inv = __expf(-(float)c * 0.14391156831212787f);
#pragma unroll
            for (int ms = 0; ms < 4; ++ms) {
                int j = ms * 4 + hi;
                f32x4 pv = xt[slot * 1024 + c * 16 + (j ^ (c & 15))];
#pragma unroll
                for (int r = 0; r < 4; ++r) {
                    int row = m0 + wm * 64 + ms * 16 + hi * 4 + r;
                    float ang = (float)(row & (S_ - 1)) * inv;
                    float sn, cs;
                    __sincosf(ang, &sn, &cs);
                    C[(size_t)row * D_ + n0 + 64 + c] = (bf16_t)(acc[ms][ns][r] * cs + pv[r] * sn);
                }
            }
        }
    }
}

// ---------------- GEMM: C[M,N] = A[M,K] * Bt[N,K]^T, fp32 out (final proj) ----------------
// Known-good 128² version (r0), default dispatch order (T1 reverted — r9 thrash).
__global__ __launch_bounds__(256) void gemm_bt_f32(const bf16_t* __restrict__ A,
                                                   const bf16_t* __restrict__ Bt,
                                                   float* __restrict__ C,
                                                   int M, int N, int K) {
    __shared__ __align__(16) bf16_t As[128 * 64];
    __shared__ __align__(16) bf16_t Bs[128 * 64];
    int t = threadIdx.x;
    int w = t >> 6, lane = t & 63, lo = lane & 15, hi = lane >> 4;
    int m0 = blockIdx.y * 128, n0 = blockIdx.x * 128;
    int wm = (w & 1) * 64, wn = (w >> 1) * 64;
    f32x4 acc[4][4] = {};
    int srow = w * 32 + (lane >> 3);
    int scol = ((lane & 7) ^ (lane >> 3)) * 8;
    const bf16_t* gA = A  + (size_t)(m0 + srow) * K + scol;
    const bf16_t* gB = Bt + (size_t)(n0 + srow) * K + scol;
    bf16_t* lA = As + w * 2048 + lane * 8;
    bf16_t* lB = Bs + w * 2048 + lane * 8;
    for (int k0 = 0; k0 < K; k0 += 64) {
#pragma unroll
        for (int i = 0; i < 4; ++i) {
            async16(gA + (size_t)(i * 8) * K + k0, lA + i * 512);
            async16(gB + (size_t)(i * 8) * K + k0, lB + i * 512);
        }
        __syncthreads();
#pragma unroll
        for (int kk = 0; kk < 2; ++kk) {
            bf16x8 af[4], bfr[4];
            int pc = (kk * 4 + hi) ^ (lo & 7);
#pragma unroll
            for (int ms = 0; ms < 4; ++ms)
                af[ms] = *(const bf16x8*)(As + (wm + ms * 16 + lo) * 64 + pc * 8);
#pragma unroll
            for (int ns = 0; ns < 4; ++ns)
                bfr[ns] = *(const bf16x8*)(Bs + (wn + ns * 16 + lo) * 64 + pc * 8);
#pragma unroll
            for (int ms = 0; ms < 4; ++ms)
#pragma unroll
                for (int ns = 0; ns < 4; ++ns)
                    acc[ms][ns] = __builtin_amdgcn_mfma_f32_16x16x32_bf16(af[ms], bfr[ns], acc[ms][ns], 0, 0, 0);
        }
        __syncthreads();
    }
#pragma unroll
    for (int ms = 0; ms < 4; ++ms)
#pragma unroll
        for (int ns = 0; ns < 4; ++ns)
#pragma unroll
            for (int r = 0; r < 4; ++r)
                C[(size_t)(m0 + wm + ms * 16 + hi * 4 + r) * N + n0 + wn + ns * 16 + lo] = acc[ms][ns][r];
}

// =====================================================================================
// Flash attention v6 (r7, measured-good): wave-pair k-split, 128-row q-tiles, 8 waves,
// dbuf K/V prefetch. T1 head-clustering reverted (r9). grid (8, 32), 512 thr.
// =====================================================================================
__global__ __launch_bounds__(512, 2) void attn_kernel(const bf16_t* __restrict__ q,
                                                      const bf16_t* __restrict__ k,
                                                      const bf16_t* __restrict__ vt,
                                                      bf16_t* __restrict__ o) {
    __shared__ __align__(16) bf16_t Ks[2][128 * 128];  // 2x32 KB [krow][d], 16-chunk swz ^ (row&15)
    __shared__ __align__(16) bf16_t Vs[2][128 * 128];  // 2x32 KB [d][kk],  16-chunk swz ^ (d&15)
    __shared__ float lred[4][2][16];                   // cross-pair l exchange
    int t = threadIdx.x;
    int w = t >> 6, lane = t & 63, lo = lane & 15, hi = lane >> 4;
    int kh = w >> 2;      // k-half owned by this wave
    int wq = w & 3;       // q-group: slices at wq*32 and wq*32+16
    int bx = blockIdx.x;  // 0..7
    int b = blockIdx.y >> 4, h = blockIdx.y & 15;
    const size_t head_off = (size_t)b * S_ * D_ + (size_t)h * HD_;
    const size_t vhead_off = ((size_t)b * D_ + (size_t)h * HD_) * S_;

#pragma unroll 1
    for (int pass = 0; pass < 2; ++pass) {
        int qt = pass ? (15 - bx) : bx;   // 128-row q-tile index
        int q0 = qt * 128;
        int qg0 = q0 + wq * 32 + lo;      // q-slice 0 row
        int qg1 = qg0 + 16;               // q-slice 1 row
        bf16x8 aq[2][4];
#pragma unroll
        for (int c = 0; c < 4; ++c) {
            aq[0][c] = *(const bf16x8*)(q + head_off + (size_t)qg0 * D_ + c * 32 + hi * 8);
            aq[1][c] = *(const bf16x8*)(q + head_off + (size_t)qg1 * D_ + c * 32 + hi * 8);
        }

        float l0 = 0.f, l1 = 0.f;
        f32x4 oacc[8][2] = {};
        int nkt = qt + 1;

        // prologue: stage tile 0 into buffer 0 (8 waves: 4 chunks each of K and V)
#pragma unroll
        for (int i = 0; i < 4; ++i) {
            int chunk = w * 4 + i;
            int r = chunk * 4 + hi;
            async16(k + head_off + (size_t)r * D_ + (lo ^ (r & 15)) * 8,
                    Ks[0] + chunk * 512 + lane * 8);
        }
#pragma unroll
        for (int i = 0; i < 4; ++i) {
            int chunk = w * 4 + i;
            int d = chunk * 4 + hi;
            async16(vt + vhead_off + (size_t)d * S_ + (lo ^ (d & 15)) * 8,
                    Vs[0] + chunk * 512 + lane * 8);
        }
        __syncthreads();  // tile 0 visible

        for (int kt = 0; kt < nkt; ++kt) {
            int k0 = kt * 128;
            int cb = kt & 1;
            if (kt + 1 < nkt) {  // prefetch tile kt+1 into the other buffer
                int kn = k0 + 128;
#pragma unroll
                for (int i = 0; i < 4; ++i) {
                    int chunk = w * 4 + i;
                    int r = chunk * 4 + hi;
                    async16(k + head_off + (size_t)(kn + r) * D_ + (lo ^ (r & 15)) * 8,
                            Ks[cb ^ 1] + chunk * 512 + lane * 8);
                }
#pragma unroll
                for (int i = 0; i < 4; ++i) {
                    int chunk = w * 4 + i;
                    int d = chunk * 4 + hi;
                    async16(vt + vhead_off + (size_t)d * S_ + kn + (lo ^ (d & 15)) * 8,
                            Vs[cb ^ 1] + chunk * 512 + lane * 8);
                }
            }

            const bf16_t* Kb = Ks[cb];
            const bf16_t* Vb = Vs[cb];
            // S^T = K * Q^T on this wave's k-half: rows kh*64 + nt*16 + (hi*4+r)
            f32x4 sacc[4][2] = {};
#pragma unroll
            for (int c = 0; c < 4; ++c) {
#pragma unroll
                for (int nt = 0; nt < 4; ++nt) {
                    int row = kh * 64 + nt * 16 + lo;
                    int pc = (c * 4 + hi) ^ lo;
                    bf16x8 ak = *(const bf16x8*)(Kb + row * 128 + pc * 8);
                    sacc[nt][0] = __builtin_amdgcn_mfma_f32_16x16x32_bf16(ak, aq[0][c], sacc[nt][0], 0, 0, 0);
                    sacc[nt][1] = __builtin_amdgcn_mfma_f32_16x16x32_bf16(ak, aq[1][c], sacc[nt][1], 0, 0, 0);
                }
            }
            bool diag = (kt == qt);
            bf16x4 pf[4][2];
#pragma unroll
            for (int nt = 0; nt < 4; ++nt) {
#pragma unroll
                for (int r = 0; r < 4; ++r) {
                    int kg = k0 + kh * 64 + nt * 16 + hi * 4 + r;
                    float e0 = __expf(fminf(sacc[nt][0][r], 60.f));
                    float e1 = __expf(fminf(sacc[nt][1][r], 60.f));
                    if (diag) {
                        if (kg > qg0) e0 = 0.f;
                        if (kg > qg1) e1 = 0.f;
                    }
                    l0 += e0; l1 += e1;
                    pf[nt][0][r] = (bf16_t)e0;
                    pf[nt][1][r] = (bf16_t)e1;
                }
            }
            // O^T[d][q] += V^T * P^T over this wave's k-half
#pragma unroll
            for (int nt = 0; nt < 4; ++nt) {
                int kkb = kh * 64 + nt * 16 + hi * 4;
                int c16 = kkb >> 3, rem = kkb & 7;
#pragma unroll
                for (int dt = 0; dt < 8; ++dt) {
                    int d = dt * 16 + lo;
                    bf16x4 av = *(const bf16x4*)(Vb + d * 128 + (c16 ^ (d & 15)) * 8 + rem);
                    oacc[dt][0] = mfma16x16x16_bf16(av, pf[nt][0], oacc[dt][0]);
                    oacc[dt][1] = mfma16x16x16_bf16(av, pf[nt][1], oacc[dt][1]);
                }
            }
            __syncthreads();  // drains prefetch + all waves' reads of cb
        }

        // ---- cross-pair reduction (waves w and w+4 share q-columns, split k) ----
        l0 += __shfl_xor(l0, 16); l0 += __shfl_xor(l0, 32);
        l1 += __shfl_xor(l1, 16); l1 += __shfl_xor(l1, 32);
        f32x4* red = (f32x4*)Ks;  // 64 KB free after last tile (no prefetch in flight)
        if (w >= 4) {
            f32x4* rp = red + (size_t)(w - 4) * 1024;
#pragma unroll
            for (int dt = 0; dt < 8; ++dt) {
                rp[(dt * 2 + 0) * 64 + lane] = oacc[dt][0];
                rp[(dt * 2 + 1) * 64 + lane] = oacc[dt][1];
            }
            if (hi == 0) { lred[w - 4][0][lo] = l0; lred[w - 4][1][lo] = l1; }
        }
        __syncthreads();
        if (w < 4) {
            f32x4* rp = red + (size_t)w * 1024;
            float rl0 = 1.0f / (l0 + lred[w][0][lo]);
            float rl1 = 1.0f / (l1 + lred[w][1][lo]);
#pragma unroll
            for (int dt = 0; dt < 8; ++dt) {
                f32x4 p0 = rp[(dt * 2 + 0) * 64 + lane];
                f32x4 p1 = rp[(dt * 2 + 1) * 64 + lane];
                bf16x4 o0 = { (bf16_t)((oacc[dt][0][0] + p0[0]) * rl0), (bf16_t)((oacc[dt][0][1] + p0[1]) * rl0),
                              (bf16_t)((oacc[dt][0][2] + p0[2]) * rl0), (bf16_t)((oacc[dt][0][3] + p0[3]) * rl0) };
                bf16x4 o1 = { (bf16_t)((oacc[dt][1][0] + p1[0]) * rl1), (bf16_t)((oacc[dt][1][1] + p1[1]) * rl1),
                              (bf16_t)((oacc[dt][1][2] + p1[2]) * rl1), (bf16_t)((oacc[dt][1][3] + p1[3]) * rl1) };
                *(bf16x4*)(o + head_off + (size_t)qg0 * D_ + dt * 16 + hi * 4) = o0;
                *(bf16x4*)(o + head_off + (size_t)qg1 * D_ + dt * 16 + hi * 4) = o1;
            }
        }
        __syncthreads();  // red region (Ks) must be free before next pass stages into it
    }
}

// ---------------- launch ----------------
extern "C" void kernel_launch(void* const* d_in, const int* in_sizes, int n_in,
                              void* d_out, int out_size, void* d_ws, size_t ws_size,
                              hipStream_t stream) {
    (void)in_sizes; (void)n_in; (void)out_size; (void)ws_size;
    const float* x  = (const float*)d_in[0];
    const float* Wq = (const float*)d_in[1];
    const float* Wk = (const float*)d_in[2];
    const float* Wv = (const float*)d_in[3];
    const float* Wo = (const float*)d_in[4];
    char* ws = (char*)d_ws;
    bf16_t* xb  = (bf16_t*)(ws);
    bf16_t* Wqb = (bf16_t*)(ws + 16777216);
    bf16_t* Wkb = (bf16_t*)(ws + 25165824);
    bf16_t* Wvb = (bf16_t*)(ws + 33554432);
    bf16_t* Wob = (bf16_t*)(ws + 41943040);
    bf16_t* qb  = (bf16_t*)(ws + 50331648);
    bf16_t* kb  = (bf16_t*)(ws + 67108864);
    bf16_t* vtb = (bf16_t*)(ws + 83886080);
    bf16_t* ob  = (bf16_t*)(ws + 100663296);
    float* out = (float*)d_out;

    f2b_multi<<<dim3(4096, 6), 256, 0, stream>>>(x, Wq, Wk, Wv, Wo, xb, Wqb, Wkb, Wvb, Wob);

    // q/k emerge rope'd — 256x128 tile: grid (48, 16) = 768 blocks
    gemm_qkv<<<dim3(48, 16), 512, 0, stream>>>(xb, Wqb, Wkb, Wvb, qb, kb, vtb);

    attn_kernel<<<dim3(8, B_ * H_), 512, 0, stream>>>(qb, kb, vtb, ob);

    gemm_bt_f32<<<dim3(D_ / 128, (B_ * S_) / 128), 256, 0, stream>>>(ob, Wob, out, B_ * S_, D_, D_);
}

// Round 11
// 358.428 us; speedup vs baseline: 1.0551x; 1.0551x over previous
//
#include <hip/hip_runtime.h>
#include <hip/hip_bf16.h>
#include <cstdint>
#include <cstddef>

#define B_ 2
#define S_ 2048
#define D_ 2048
#define H_ 16
#define HD_ 128

typedef __bf16 bf16_t;
typedef __bf16 bf16x8 __attribute__((ext_vector_type(8)));
typedef __bf16 bf16x4 __attribute__((ext_vector_type(4)));
typedef short s16x4 __attribute__((ext_vector_type(4)));
typedef float f32x4 __attribute__((ext_vector_type(4)));

__device__ __forceinline__ void async16(const bf16_t* g, bf16_t* l) {
    __builtin_amdgcn_global_load_lds(
        (const __attribute__((address_space(1))) unsigned int*)g,
        (__attribute__((address_space(3))) unsigned int*)l, 16, 0, 0);
}

// K=16 bf16 MFMA with builtin-name portability chain
__device__ __forceinline__ f32x4 mfma16x16x16_bf16(bf16x4 a, bf16x4 b, f32x4 c) {
#if __has_builtin(__builtin_amdgcn_mfma_f32_16x16x16_bf16)
    return __builtin_amdgcn_mfma_f32_16x16x16_bf16(a, b, c, 0, 0, 0);
#elif __has_builtin(__builtin_amdgcn_mfma_f32_16x16x16bf16_1k)
    return __builtin_amdgcn_mfma_f32_16x16x16bf16_1k(
        __builtin_bit_cast(s16x4, a), __builtin_bit_cast(s16x4, b), c, 0, 0, 0);
#else
    f32x4 d = c;
    asm("v_mfma_f32_16x16x16_bf16 %0, %1, %2, %0" : "+v"(d) : "v"(a), "v"(b));
    return d;
#endif
}

// ---------------- fused fp32 -> bf16 convert; Wq gets 1/sqrt(HD) folded in ----------------
// r11: 8 floats/thread (2x float4), grid (2048, 6).
__global__ void f2b_multi(const float* __restrict__ x, const float* __restrict__ wq,
                          const float* __restrict__ wk, const float* __restrict__ wv,
                          const float* __restrict__ wo, bf16_t* __restrict__ xb,
                          bf16_t* __restrict__ wqb, bf16_t* __restrict__ wkb,
                          bf16_t* __restrict__ wvb, bf16_t* __restrict__ wob) {
    const float* in; bf16_t* out;
    float sc = 1.0f;
    switch (blockIdx.y) {
        case 0: in = x;            out = xb;            break;
        case 1: in = x + 4194304;  out = xb + 4194304;  break;
        case 2: in = wq;           out = wqb; sc = 0.08838834764831845f; break;
        case 3: in = wk;           out = wkb;           break;
        case 4: in = wv;           out = wvb;           break;
        default: in = wo;          out = wob;           break;
    }
    int i = (blockIdx.x * blockDim.x + threadIdx.x) * 8;
    float4 v0 = *(const float4*)(in + i);
    float4 v1 = *(const float4*)(in + i + 4);
    bf16x4 o0 = { (bf16_t)(v0.x * sc), (bf16_t)(v0.y * sc), (bf16_t)(v0.z * sc), (bf16_t)(v0.w * sc) };
    bf16x4 o1 = { (bf16_t)(v1.x * sc), (bf16_t)(v1.y * sc), (bf16_t)(v1.z * sc), (bf16_t)(v1.w * sc) };
    *(bf16x4*)(out + i) = o0;
    *(bf16x4*)(out + i + 4) = o1;
}

// =====================================================================================
// BK=64 GEMM core (round-0 verified): As/Bs [128][64]; chunk swizzle phys=log^(row&7);
// pre-swizzled global src, linear LDS dest; read pc=(kk*4+hi)^(lo&7) -> 0 conflicts.
// RoPE fused into q/k epilogue (r6, verified). Closed levers on this problem:
// pipelining (r2/r3/r5), T1 XCD swizzle (r9: 3x FETCH thrash), 256-tile (r10: cold-
// dispatch pathology at 2 blocks/CU). Multi-block 128² is the measured optimum.
// =====================================================================================

// ---------------- fused QKV GEMM + RoPE: [q|k|v] = x @ W^T; V written transposed ----------------
// grid (48, 32): seg = bx/16 (0=q,1=k,2=v), 256 thr.
__global__ __launch_bounds__(256) void gemm_qkv(const bf16_t* __restrict__ A,
                                                const bf16_t* __restrict__ Wq,
                                                const bf16_t* __restrict__ Wk,
                                                const bf16_t* __restrict__ Wv,
                                                bf16_t* __restrict__ qb,
                                                bf16_t* __restrict__ kb,
                                                bf16_t* __restrict__ vtb) {
    __shared__ __align__(16) bf16_t sbuf[2 * 128 * 64];   // As | Bs, reused as f32 exchange
    bf16_t* As = sbuf;
    bf16_t* Bs = sbuf + 8192;
    const int K = D_;
    int t = threadIdx.x;
    int w = t >> 6, lane = t & 63, lo = lane & 15, hi = lane >> 4;
    int seg = blockIdx.x >> 4;
    int n0 = (blockIdx.x & 15) * 128;
    int m0 = blockIdx.y * 128;
    const bf16_t* Bt = (seg == 0) ? Wq : (seg == 1) ? Wk : Wv;
    int wm = (w & 1) * 64, wn = (w >> 1) * 64;
    f32x4 acc[4][4] = {};
    int srow = w * 32 + (lane >> 3);
    int scol = ((lane & 7) ^ (lane >> 3)) * 8;
    const bf16_t* gA = A  + (size_t)(m0 + srow) * K + scol;
    const bf16_t* gB = Bt + (size_t)(n0 + srow) * K + scol;
    bf16_t* lA = As + w * 2048 + lane * 8;
    bf16_t* lB = Bs + w * 2048 + lane * 8;
    for (int k0 = 0; k0 < K; k0 += 64) {
#pragma unroll
        for (int i = 0; i < 4; ++i) {
            async16(gA + (size_t)(i * 8) * K + k0, lA + i * 512);
            async16(gB + (size_t)(i * 8) * K + k0, lB + i * 512);
        }
        __syncthreads();
#pragma unroll
        for (int kk = 0; kk < 2; ++kk) {
            bf16x8 af[4], bfr[4];
            int pc = (kk * 4 + hi) ^ (lo & 7);
#pragma unroll
            for (int ms = 0; ms < 4; ++ms)
                af[ms] = *(const bf16x8*)(As + (wm + ms * 16 + lo) * 64 + pc * 8);
#pragma unroll
            for (int ns = 0; ns < 4; ++ns)
                bfr[ns] = *(const bf16x8*)(Bs + (wn + ns * 16 + lo) * 64 + pc * 8);
#pragma unroll
            for (int ms = 0; ms < 4; ++ms)
#pragma unroll
                for (int ns = 0; ns < 4; ++ns)
                    acc[ms][ns] = __builtin_amdgcn_mfma_f32_16x16x32_bf16(af[ms], bfr[ns], acc[ms][ns], 0, 0, 0);
        }
        __syncthreads();
    }

    if (seg == 2) {
        // V transposed: vtb[b][d][s] (no rope on V)
#pragma unroll
        for (int ms = 0; ms < 4; ++ms) {
            int mrow = m0 + wm + ms * 16 + hi * 4;
            int bb = mrow >> 11, s = mrow & (S_ - 1);
#pragma unroll
            for (int ns = 0; ns < 4; ++ns) {
                int d = n0 + wn + ns * 16 + lo;
                bf16x4 pv = { (bf16_t)acc[ms][ns][0], (bf16_t)acc[ms][ns][1],
                              (bf16_t)acc[ms][ns][2], (bf16_t)acc[ms][ns][3] };
                *(bf16x4*)(vtb + (size_t)bb * D_ * S_ + (size_t)d * S_ + s) = pv;
            }
        }
        return;
    }

    // ---------------- RoPE-fused q/k epilogue ----------------
    bf16_t* C = (seg == 0) ? qb : kb;
    f32x4* xt = (f32x4*)sbuf;           // 8192 f32 = 32 KB, two 64x64 tiles
    int slot = w & 1;
    bool upper = (wn != 0);             // holds d in [64,128)

    if (upper) {
#pragma unroll
        for (int ms = 0; ms < 4; ++ms)
#pragma unroll
            for (int ns = 0; ns < 4; ++ns) {
                int c = ns * 16 + lo, j = ms * 4 + hi;
                xt[slot * 1024 + c * 16 + (j ^ (c & 15))] = acc[ms][ns];
            }
    }
    __syncthreads();
    if (!upper) {
        // d = c in [0,64): out = x*cos - x[d+64]*sin
#pragma unroll
        for (int ns = 0; ns < 4; ++ns) {
            int c = ns * 16 + lo;
            float inv = __expf(-(float)c * 0.14391156831212787f);
#pragma unroll
            for (int ms = 0; ms < 4; ++ms) {
                int j = ms * 4 + hi;
                f32x4 pv = xt[slot * 1024 + c * 16 + (j ^ (c & 15))];
#pragma unroll
                for (int r = 0; r < 4; ++r) {
                    int row = m0 + wm + ms * 16 + hi * 4 + r;
                    float ang = (float)(row & (S_ - 1)) * inv;
                    float sn, cs;
                    __sincosf(ang, &sn, &cs);
                    C[(size_t)row * D_ + n0 + c] = (bf16_t)(acc[ms][ns][r] * cs - pv[r] * sn);
                }
            }
        }
    }
    __syncthreads();
    if (!upper) {
#pragma unroll
        for (int ms = 0; ms < 4; ++ms)
#pragma unroll
            for (int ns = 0; ns < 4; ++ns) {
                int c = ns * 16 + lo, j = ms * 4 + hi;
                xt[slot * 1024 + c * 16 + (j ^ (c & 15))] = acc[ms][ns];
            }
    }
    __syncthreads();
    if (upper) {
        // d = 64 + c: out = x*cos + x[d-64]*sin  (cos/sin index = c)
#pragma unroll
        for (int ns = 0; ns < 4; ++ns) {
            int c = ns * 16 + lo;
            float inv = __expf(-(float)c * 0.14391156831212787f);
#pragma unroll
            for (int ms = 0; ms < 4; ++ms) {
                int j = ms * 4 + hi;
                f32x4 pv = xt[slot * 1024 + c * 16 + (j ^ (c & 15))];
#pragma unroll
                for (int r = 0; r < 4; ++r) {
                    int row = m0 + wm + ms * 16 + hi * 4 + r;
                    float ang = (float)(row & (S_ - 1)) * inv;
                    float sn, cs;
                    __sincosf(ang, &sn, &cs);
                    C[(size_t)row * D_ + n0 + 64 + c] = (bf16_t)(acc[ms][ns][r] * cs + pv[r] * sn);
                }
            }
        }
    }
}

// ---------------- GEMM: C[M,N] = A[M,K] * Bt[N,K]^T, fp32 out (final proj) ----------------
__global__ __launch_bounds__(256) void gemm_bt_f32(const bf16_t* __restrict__ A,
                                                   const bf16_t* __restrict__ Bt,
                                                   float* __restrict__ C,
                                                   int M, int N, int K) {
    __shared__ __align__(16) bf16_t As[128 * 64];
    __shared__ __align__(16) bf16_t Bs[128 * 64];
    int t = threadIdx.x;
    int w = t >> 6, lane = t & 63, lo = lane & 15, hi = lane >> 4;
    int m0 = blockIdx.y * 128, n0 = blockIdx.x * 128;
    int wm = (w & 1) * 64, wn = (w >> 1) * 64;
    f32x4 acc[4][4] = {};
    int srow = w * 32 + (lane >> 3);
    int scol = ((lane & 7) ^ (lane >> 3)) * 8;
    const bf16_t* gA = A  + (size_t)(m0 + srow) * K + scol;
    const bf16_t* gB = Bt + (size_t)(n0 + srow) * K + scol;
    bf16_t* lA = As + w * 2048 + lane * 8;
    bf16_t* lB = Bs + w * 2048 + lane * 8;
    for (int k0 = 0; k0 < K; k0 += 64) {
#pragma unroll
        for (int i = 0; i < 4; ++i) {
            async16(gA + (size_t)(i * 8) * K + k0, lA + i * 512);
            async16(gB + (size_t)(i * 8) * K + k0, lB + i * 512);
        }
        __syncthreads();
#pragma unroll
        for (int kk = 0; kk < 2; ++kk) {
            bf16x8 af[4], bfr[4];
            int pc = (kk * 4 + hi) ^ (lo & 7);
#pragma unroll
            for (int ms = 0; ms < 4; ++ms)
                af[ms] = *(const bf16x8*)(As + (wm + ms * 16 + lo) * 64 + pc * 8);
#pragma unroll
            for (int ns = 0; ns < 4; ++ns)
                bfr[ns] = *(const bf16x8*)(Bs + (wn + ns * 16 + lo) * 64 + pc * 8);
#pragma unroll
            for (int ms = 0; ms < 4; ++ms)
#pragma unroll
                for (int ns = 0; ns < 4; ++ns)
                    acc[ms][ns] = __builtin_amdgcn_mfma_f32_16x16x32_bf16(af[ms], bfr[ns], acc[ms][ns], 0, 0, 0);
        }
        __syncthreads();
    }
#pragma unroll
    for (int ms = 0; ms < 4; ++ms)
#pragma unroll
        for (int ns = 0; ns < 4; ++ns)
#pragma unroll
            for (int r = 0; r < 4; ++r)
                C[(size_t)(m0 + wm + ms * 16 + hi * 4 + r) * N + n0 + wn + ns * 16 + lo] = acc[ms][ns][r];
}

// =====================================================================================
// Flash attention v6 (r7, measured-good): wave-pair k-split, 128-row q-tiles, 8 waves,
// dbuf K/V prefetch. grid (8, 32), 512 thr.
// =====================================================================================
__global__ __launch_bounds__(512, 2) void attn_kernel(const bf16_t* __restrict__ q,
                                                      const bf16_t* __restrict__ k,
                                                      const bf16_t* __restrict__ vt,
                                                      bf16_t* __restrict__ o) {
    __shared__ __align__(16) bf16_t Ks[2][128 * 128];  // 2x32 KB [krow][d], 16-chunk swz ^ (row&15)
    __shared__ __align__(16) bf16_t Vs[2][128 * 128];  // 2x32 KB [d][kk],  16-chunk swz ^ (d&15)
    __shared__ float lred[4][2][16];                   // cross-pair l exchange
    int t = threadIdx.x;
    int w = t >> 6, lane = t & 63, lo = lane & 15, hi = lane >> 4;
    int kh = w >> 2;      // k-half owned by this wave
    int wq = w & 3;       // q-group: slices at wq*32 and wq*32+16
    int bx = blockIdx.x;  // 0..7
    int b = blockIdx.y >> 4, h = blockIdx.y & 15;
    const size_t head_off = (size_t)b * S_ * D_ + (size_t)h * HD_;
    const size_t vhead_off = ((size_t)b * D_ + (size_t)h * HD_) * S_;

#pragma unroll 1
    for (int pass = 0; pass < 2; ++pass) {
        int qt = pass ? (15 - bx) : bx;   // 128-row q-tile index
        int q0 = qt * 128;
        int qg0 = q0 + wq * 32 + lo;      // q-slice 0 row
        int qg1 = qg0 + 16;               // q-slice 1 row
        bf16x8 aq[2][4];
#pragma unroll
        for (int c = 0; c < 4; ++c) {
            aq[0][c] = *(const bf16x8*)(q + head_off + (size_t)qg0 * D_ + c * 32 + hi * 8);
            aq[1][c] = *(const bf16x8*)(q + head_off + (size_t)qg1 * D_ + c * 32 + hi * 8);
        }

        float l0 = 0.f, l1 = 0.f;
        f32x4 oacc[8][2] = {};
        int nkt = qt + 1;

        // prologue: stage tile 0 into buffer 0 (8 waves: 4 chunks each of K and V)
#pragma unroll
        for (int i = 0; i < 4; ++i) {
            int chunk = w * 4 + i;
            int r = chunk * 4 + hi;
            async16(k + head_off + (size_t)r * D_ + (lo ^ (r & 15)) * 8,
                    Ks[0] + chunk * 512 + lane * 8);
        }
#pragma unroll
        for (int i = 0; i < 4; ++i) {
            int chunk = w * 4 + i;
            int d = chunk * 4 + hi;
            async16(vt + vhead_off + (size_t)d * S_ + (lo ^ (d & 15)) * 8,
                    Vs[0] + chunk * 512 + lane * 8);
        }
        __syncthreads();  // tile 0 visible

        for (int kt = 0; kt < nkt; ++kt) {
            int k0 = kt * 128;
            int cb = kt & 1;
            if (kt + 1 < nkt) {  // prefetch tile kt+1 into the other buffer
                int kn = k0 + 128;
#pragma unroll
                for (int i = 0; i < 4; ++i) {
                    int chunk = w * 4 + i;
                    int r = chunk * 4 + hi;
                    async16(k + head_off + (size_t)(kn + r) * D_ + (lo ^ (r & 15)) * 8,
                            Ks[cb ^ 1] + chunk * 512 + lane * 8);
                }
#pragma unroll
                for (int i = 0; i < 4; ++i) {
                    int chunk = w * 4 + i;
                    int d = chunk * 4 + hi;
                    async16(vt + vhead_off + (size_t)d * S_ + kn + (lo ^ (d & 15)) * 8,
                            Vs[cb ^ 1] + chunk * 512 + lane * 8);
                }
            }

            const bf16_t* Kb = Ks[cb];
            const bf16_t* Vb = Vs[cb];
            // S^T = K * Q^T on this wave's k-half: rows kh*64 + nt*16 + (hi*4+r)
            f32x4 sacc[4][2] = {};
#pragma unroll
            for (int c = 0; c < 4; ++c) {
#pragma unroll
                for (int nt = 0; nt < 4; ++nt) {
                    int row = kh * 64 + nt * 16 + lo;
                    int pc = (c * 4 + hi) ^ lo;
                    bf16x8 ak = *(const bf16x8*)(Kb + row * 128 + pc * 8);
                    sacc[nt][0] = __builtin_amdgcn_mfma_f32_16x16x32_bf16(ak, aq[0][c], sacc[nt][0], 0, 0, 0);
                    sacc[nt][1] = __builtin_amdgcn_mfma_f32_16x16x32_bf16(ak, aq[1][c], sacc[nt][1], 0, 0, 0);
                }
            }
            bool diag = (kt == qt);
            bf16x4 pf[4][2];
#pragma unroll
            for (int nt = 0; nt < 4; ++nt) {
#pragma unroll
                for (int r = 0; r < 4; ++r) {
                    int kg = k0 + kh * 64 + nt * 16 + hi * 4 + r;
                    float e0 = __expf(fminf(sacc[nt][0][r], 60.f));
                    float e1 = __expf(fminf(sacc[nt][1][r], 60.f));
                    if (diag) {
                        if (kg > qg0) e0 = 0.f;
                        if (kg > qg1) e1 = 0.f;
                    }
                    l0 += e0; l1 += e1;
                    pf[nt][0][r] = (bf16_t)e0;
                    pf[nt][1][r] = (bf16_t)e1;
                }
            }
            // O^T[d][q] += V^T * P^T over this wave's k-half
#pragma unroll
            for (int nt = 0; nt < 4; ++nt) {
                int kkb = kh * 64 + nt * 16 + hi * 4;
                int c16 = kkb >> 3, rem = kkb & 7;
#pragma unroll
                for (int dt = 0; dt < 8; ++dt) {
                    int d = dt * 16 + lo;
                    bf16x4 av = *(const bf16x4*)(Vb + d * 128 + (c16 ^ (d & 15)) * 8 + rem);
                    oacc[dt][0] = mfma16x16x16_bf16(av, pf[nt][0], oacc[dt][0]);
                    oacc[dt][1] = mfma16x16x16_bf16(av, pf[nt][1], oacc[dt][1]);
                }
            }
            __syncthreads();  // drains prefetch + all waves' reads of cb
        }

        // ---- cross-pair reduction (waves w and w+4 share q-columns, split k) ----
        l0 += __shfl_xor(l0, 16); l0 += __shfl_xor(l0, 32);
        l1 += __shfl_xor(l1, 16); l1 += __shfl_xor(l1, 32);
        f32x4* red = (f32x4*)Ks;  // 64 KB free after last tile (no prefetch in flight)
        if (w >= 4) {
            f32x4* rp = red + (size_t)(w - 4) * 1024;
#pragma unroll
            for (int dt = 0; dt < 8; ++dt) {
                rp[(dt * 2 + 0) * 64 + lane] = oacc[dt][0];
                rp[(dt * 2 + 1) * 64 + lane] = oacc[dt][1];
            }
            if (hi == 0) { lred[w - 4][0][lo] = l0; lred[w - 4][1][lo] = l1; }
        }
        __syncthreads();
        if (w < 4) {
            f32x4* rp = red + (size_t)w * 1024;
            float rl0 = 1.0f / (l0 + lred[w][0][lo]);
            float rl1 = 1.0f / (l1 + lred[w][1][lo]);
#pragma unroll
            for (int dt = 0; dt < 8; ++dt) {
                f32x4 p0 = rp[(dt * 2 + 0) * 64 + lane];
                f32x4 p1 = rp[(dt * 2 + 1) * 64 + lane];
                bf16x4 o0 = { (bf16_t)((oacc[dt][0][0] + p0[0]) * rl0), (bf16_t)((oacc[dt][0][1] + p0[1]) * rl0),
                              (bf16_t)((oacc[dt][0][2] + p0[2]) * rl0), (bf16_t)((oacc[dt][0][3] + p0[3]) * rl0) };
                bf16x4 o1 = { (bf16_t)((oacc[dt][1][0] + p1[0]) * rl1), (bf16_t)((oacc[dt][1][1] + p1[1]) * rl1),
                              (bf16_t)((oacc[dt][1][2] + p1[2]) * rl1), (bf16_t)((oacc[dt][1][3] + p1[3]) * rl1) };
                *(bf16x4*)(o + head_off + (size_t)qg0 * D_ + dt * 16 + hi * 4) = o0;
                *(bf16x4*)(o + head_off + (size_t)qg1 * D_ + dt * 16 + hi * 4) = o1;
            }
        }
        __syncthreads();  // red region (Ks) must be free before next pass stages into it
    }
}

// ---------------- launch ----------------
extern "C" void kernel_launch(void* const* d_in, const int* in_sizes, int n_in,
                              void* d_out, int out_size, void* d_ws, size_t ws_size,
                              hipStream_t stream) {
    (void)in_sizes; (void)n_in; (void)out_size; (void)ws_size;
    const float* x  = (const float*)d_in[0];
    const float* Wq = (const float*)d_in[1];
    const float* Wk = (const float*)d_in[2];
    const float* Wv = (const float*)d_in[3];
    const float* Wo = (const float*)d_in[4];
    char* ws = (char*)d_ws;
    bf16_t* xb  = (bf16_t*)(ws);
    bf16_t* Wqb = (bf16_t*)(ws + 16777216);
    bf16_t* Wkb = (bf16_t*)(ws + 25165824);
    bf16_t* Wvb = (bf16_t*)(ws + 33554432);
    bf16_t* Wob = (bf16_t*)(ws + 41943040);
    bf16_t* qb  = (bf16_t*)(ws + 50331648);
    bf16_t* kb  = (bf16_t*)(ws + 67108864);
    bf16_t* vtb = (bf16_t*)(ws + 83886080);
    bf16_t* ob  = (bf16_t*)(ws + 100663296);
    float* out = (float*)d_out;

    f2b_multi<<<dim3(2048, 6), 256, 0, stream>>>(x, Wq, Wk, Wv, Wo, xb, Wqb, Wkb, Wvb, Wob);

    // q/k emerge rope'd — no separate rope kernel
    gemm_qkv<<<dim3(48, 32), 256, 0, stream>>>(xb, Wqb, Wkb, Wvb, qb, kb, vtb);

    attn_kernel<<<dim3(8, B_ * H_), 512, 0, stream>>>(qb, kb, vtb, ob);

    gemm_bt_f32<<<dim3(D_ / 128, (B_ * S_) / 128), 256, 0, stream>>>(ob, Wob, out, B_ * S_, D_, D_);
}